// Round 1
// baseline (193.716 us; speedup 1.0000x reference)
//
#include <hip/hip_runtime.h>
#include <math.h>

// Problem constants
#define NB 16
#define NL 128
#define DIN 512
#define NH 256
#define NTAGS 45
#define NM (NB*NL)          // 2048 rows
#define NJ (NL+1)           // 129

// ws layout (floats)
#define HID_OFF 0
#define U_OFF   (NM*NH)                 // 524288
#define V_OFF   (U_OFF + NM*NH)         // 1048576
#define ACC_OFF (V_OFF + NB*NJ*NH)      // 1576960

// ---------------------------------------------------------------------------
// Kernel A: hidden = relu(C @ W1 + b1)   (2048x512)@(512x256)
// 64x64 tile, 256 threads, 4x4 per thread, BK=16
// ---------------------------------------------------------------------------
__global__ __launch_bounds__(256) void gemm_hidden(
    const float* __restrict__ A,   // 2048 x 512
    const float* __restrict__ W,   // 512 x 256
    const float* __restrict__ bias,// 256
    float* __restrict__ out)       // 2048 x 256
{
    const int K = DIN, N = NH;
    __shared__ float As[16][64];   // transposed: As[k][m]
    __shared__ float Bs[16][64];   // Bs[k][n]
    int m0 = blockIdx.x * 64;
    int n0 = blockIdx.y * 64;
    int tid = threadIdx.x;
    int tm = tid >> 4, tn = tid & 15;
    int lm = tid >> 2;            // 0..63
    int lk = (tid & 3) * 4;       // 0,4,8,12
    int bk = tid >> 4;            // 0..15
    int bn = (tid & 15) * 4;      // 0..60
    float acc[4][4] = {{0.f}};

    for (int k0 = 0; k0 < K; k0 += 16) {
        float4 a4 = *(const float4*)&A[(m0 + lm) * K + k0 + lk];
        As[lk + 0][lm] = a4.x; As[lk + 1][lm] = a4.y;
        As[lk + 2][lm] = a4.z; As[lk + 3][lm] = a4.w;
        float4 b4 = *(const float4*)&W[(k0 + bk) * N + n0 + bn];
        *(float4*)&Bs[bk][bn] = b4;
        __syncthreads();
        #pragma unroll
        for (int kk = 0; kk < 16; kk++) {
            float4 av = *(const float4*)&As[kk][tm * 4];
            float4 bv = *(const float4*)&Bs[kk][tn * 4];
            float ar[4] = {av.x, av.y, av.z, av.w};
            float br[4] = {bv.x, bv.y, bv.z, bv.w};
            #pragma unroll
            for (int r = 0; r < 4; r++)
                #pragma unroll
                for (int c = 0; c < 4; c++)
                    acc[r][c] += ar[r] * br[c];
        }
        __syncthreads();
    }
    int col = n0 + tn * 4;
    float4 bb = *(const float4*)&bias[col];
    float bcol[4] = {bb.x, bb.y, bb.z, bb.w};
    #pragma unroll
    for (int r = 0; r < 4; r++) {
        int row = m0 + tm * 4 + r;
        float4 o;
        o.x = fmaxf(acc[r][0] + bcol[0], 0.f);
        o.y = fmaxf(acc[r][1] + bcol[1], 0.f);
        o.z = fmaxf(acc[r][2] + bcol[2], 0.f);
        o.w = fmaxf(acc[r][3] + bcol[3], 0.f);
        *(float4*)&out[row * N + col] = o;
    }
}

// ---------------------------------------------------------------------------
// Kernel B: u = hidden@Wa + bp ; hv = hidden@Wb scattered into v[b][1+i][k]
// treated as GEMM M=2048, N=512, K=256 against Wp (512x256)
// ---------------------------------------------------------------------------
__global__ __launch_bounds__(256) void gemm_uv(
    const float* __restrict__ hidden, // 2048 x 256
    const float* __restrict__ Wp,     // 512 x 256
    const float* __restrict__ bp,     // 256
    float* __restrict__ u,            // 2048 x 256
    float* __restrict__ v)            // 16 x 129 x 256
{
    const int K = NH;
    __shared__ float As[16][64];
    __shared__ float Bs[16][64];
    int m0 = blockIdx.x * 64;
    int n0 = blockIdx.y * 64;     // 0..448 ; n0<256 -> u part, else v part
    bool isU = (n0 < NH);
    int tid = threadIdx.x;
    int tm = tid >> 4, tn = tid & 15;
    int lm = tid >> 2;
    int lk = (tid & 3) * 4;
    int bk = tid >> 4;
    int bn = (tid & 15) * 4;
    float acc[4][4] = {{0.f}};

    for (int k0 = 0; k0 < K; k0 += 16) {
        float4 a4 = *(const float4*)&hidden[(m0 + lm) * K + k0 + lk];
        As[lk + 0][lm] = a4.x; As[lk + 1][lm] = a4.y;
        As[lk + 2][lm] = a4.z; As[lk + 3][lm] = a4.w;
        // B matrix: col n<256 -> Wp[c][n]; col n>=256 -> Wp[256+c][n-256]
        int c = k0 + bk;
        float4 b4;
        if (isU) b4 = *(const float4*)&Wp[c * NH + n0 + bn];
        else     b4 = *(const float4*)&Wp[(NH + c) * NH + (n0 - NH) + bn];
        *(float4*)&Bs[bk][bn] = b4;
        __syncthreads();
        #pragma unroll
        for (int kk = 0; kk < 16; kk++) {
            float4 av = *(const float4*)&As[kk][tm * 4];
            float4 bv = *(const float4*)&Bs[kk][tn * 4];
            float ar[4] = {av.x, av.y, av.z, av.w};
            float br[4] = {bv.x, bv.y, bv.z, bv.w};
            #pragma unroll
            for (int r = 0; r < 4; r++)
                #pragma unroll
                for (int cc = 0; cc < 4; cc++)
                    acc[r][cc] += ar[r] * br[cc];
        }
        __syncthreads();
    }
    if (isU) {
        int col = n0 + tn * 4;
        float4 bb = *(const float4*)&bp[col];
        float bcol[4] = {bb.x, bb.y, bb.z, bb.w};
        #pragma unroll
        for (int r = 0; r < 4; r++) {
            int row = m0 + tm * 4 + r;
            float4 o;
            o.x = acc[r][0] + bcol[0];
            o.y = acc[r][1] + bcol[1];
            o.z = acc[r][2] + bcol[2];
            o.w = acc[r][3] + bcol[3];
            *(float4*)&u[row * NH + col] = o;
        }
    } else {
        int col = (n0 - NH) + tn * 4;
        #pragma unroll
        for (int r = 0; r < 4; r++) {
            int row = m0 + tm * 4 + r;
            int b = row >> 7, i = row & 127;
            float4 o;
            o.x = acc[r][0]; o.y = acc[r][1];
            o.z = acc[r][2]; o.w = acc[r][3];
            *(float4*)&v[(b * NJ + 1 + i) * NH + col] = o;
        }
    }
}

// ---------------------------------------------------------------------------
// rootv: v[b][0][k] = sum_c root[c] * Wp[256+c][k]
// ---------------------------------------------------------------------------
__global__ __launch_bounds__(256) void rootv_kernel(
    const float* __restrict__ root, const float* __restrict__ Wp,
    float* __restrict__ v)
{
    int k = threadIdx.x;
    float acc = 0.f;
    for (int c = 0; c < NH; c++)
        acc += root[c] * Wp[(NH + c) * NH + k];
    #pragma unroll
    for (int b = 0; b < NB; b++)
        v[(b * NJ) * NH + k] = acc;
}

// ---------------------------------------------------------------------------
// Kernel C: per-(b,i) row -> arc CE + label CE, atomicAdd into accum
// ---------------------------------------------------------------------------
__global__ __launch_bounds__(256) void row_loss(
    const float* __restrict__ u, const float* __restrict__ v,
    const float* __restrict__ W_arc, const float* __restrict__ b_arc,
    const float* __restrict__ W_lab, const float* __restrict__ b_lab,
    const int* __restrict__ slens, const int* __restrict__ arcs,
    const int* __restrict__ labels, float* __restrict__ accum)
{
    int bi = blockIdx.x;
    int b = bi >> 7, i = bi & 127;
    if (i >= slens[b]) return;

    __shared__ float u_s[NH], wa_s[NH], s_s[256], red[256], sel_s[NH];
    int tid = threadIdx.x;
    u_s[tid] = u[bi * NH + tid];
    wa_s[tid] = W_arc[tid];
    __syncthreads();

    // phase 1: 129 arc scores
    float sj = -INFINITY;
    if (tid < NJ) {
        const float* vr = &v[(b * NJ + tid) * NH];
        float acc = 0.f;
        #pragma unroll 8
        for (int k = 0; k < NH; k += 4) {
            float4 vv = *(const float4*)&vr[k];
            acc += fmaxf(u_s[k + 0] + vv.x, 0.f) * wa_s[k + 0];
            acc += fmaxf(u_s[k + 1] + vv.y, 0.f) * wa_s[k + 1];
            acc += fmaxf(u_s[k + 2] + vv.z, 0.f) * wa_s[k + 2];
            acc += fmaxf(u_s[k + 3] + vv.w, 0.f) * wa_s[k + 3];
        }
        sj = acc + b_arc[0];
    }
    s_s[tid] = sj;
    red[tid] = sj;
    // max reduction over 256 (tail is -inf)
    for (int off = 128; off > 0; off >>= 1) {
        __syncthreads();
        if (tid < off) red[tid] = fmaxf(red[tid], red[tid + off]);
    }
    __syncthreads();
    float mx = red[0];
    __syncthreads();
    red[tid] = (tid < NJ) ? expf(s_s[tid] - mx) : 0.f;
    for (int off = 128; off > 0; off >>= 1) {
        __syncthreads();
        if (tid < off) red[tid] += red[tid + off];
    }
    __syncthreads();
    float logZ = mx + logf(red[0]);
    int arc = arcs[bi];
    float arc_ce = logZ - s_s[arc];
    __syncthreads();

    // phase 2: label head on gathered arc row
    {
        const float* vr = &v[(b * NJ + arc) * NH];
        sel_s[tid] = fmaxf(u_s[tid] + vr[tid], 0.f);
    }
    __syncthreads();
    float lt = -INFINITY;
    if (tid < NTAGS) {
        float acc = b_lab[tid];
        for (int k = 0; k < NH; k++)
            acc += sel_s[k] * W_lab[k * NTAGS + tid];
        lt = acc;
    }
    s_s[tid] = lt;
    red[tid] = lt;
    for (int off = 128; off > 0; off >>= 1) {
        __syncthreads();
        if (tid < off) red[tid] = fmaxf(red[tid], red[tid + off]);
    }
    __syncthreads();
    float mx2 = red[0];
    __syncthreads();
    red[tid] = (tid < NTAGS) ? expf(s_s[tid] - mx2) : 0.f;
    for (int off = 128; off > 0; off >>= 1) {
        __syncthreads();
        if (tid < off) red[tid] += red[tid + off];
    }
    __syncthreads();
    float logZ2 = mx2 + logf(red[0]);
    float lab_ce = logZ2 - s_s[labels[bi]];

    if (tid == 0) atomicAdd(accum, arc_ce + lab_ce);
}

// ---------------------------------------------------------------------------
// finalize: out = 0.5 * accum / max(sum(slens), 1)
// ---------------------------------------------------------------------------
__global__ void finalize_kernel(const float* __restrict__ accum,
                                const int* __restrict__ slens,
                                float* __restrict__ out)
{
    if (threadIdx.x == 0) {
        int d = 0;
        #pragma unroll
        for (int b = 0; b < NB; b++) d += slens[b];
        float denom = fmaxf((float)d, 1.f);
        out[0] = 0.5f * accum[0] / denom;
    }
}

extern "C" void kernel_launch(void* const* d_in, const int* in_sizes, int n_in,
                              void* d_out, int out_size, void* d_ws, size_t ws_size,
                              hipStream_t stream) {
    (void)in_sizes; (void)n_in; (void)out_size; (void)ws_size;
    const float* ctx   = (const float*)d_in[0];
    const int*   slens = (const int*)  d_in[1];
    const int*   arcs  = (const int*)  d_in[2];
    const int*   labs  = (const int*)  d_in[3];
    const float* W1    = (const float*)d_in[4];
    const float* b1    = (const float*)d_in[5];
    const float* root  = (const float*)d_in[6];
    const float* Wp    = (const float*)d_in[7];
    const float* bp    = (const float*)d_in[8];
    const float* W_arc = (const float*)d_in[9];
    const float* b_arc = (const float*)d_in[10];
    const float* W_lab = (const float*)d_in[11];
    const float* b_lab = (const float*)d_in[12];
    float* out = (float*)d_out;

    float* ws     = (float*)d_ws;
    float* hidden = ws + HID_OFF;
    float* u      = ws + U_OFF;
    float* v      = ws + V_OFF;
    float* accum  = ws + ACC_OFF;

    hipMemsetAsync(accum, 0, sizeof(float), stream);

    rootv_kernel<<<1, 256, 0, stream>>>(root, Wp, v);
    gemm_hidden<<<dim3(NM / 64, NH / 64), 256, 0, stream>>>(ctx, W1, b1, hidden);
    gemm_uv<<<dim3(NM / 64, (2 * NH) / 64), 256, 0, stream>>>(hidden, Wp, bp, u, v);
    row_loss<<<NM, 256, 0, stream>>>(u, v, W_arc, b_arc, W_lab, b_lab,
                                     slens, arcs, labs, accum);
    finalize_kernel<<<1, 64, 0, stream>>>(accum, slens, out);
}

// Round 2
// 180.818 us; speedup vs baseline: 1.0713x; 1.0713x over previous
//
#include <hip/hip_runtime.h>
#include <math.h>

// Problem constants
#define NB 16
#define NL 128
#define DIN 512
#define NH 256
#define NTAGS 45
#define NM (NB*NL)          // 2048 rows
#define NJ (NL+1)           // 129 (real arc columns)
#define NJP 132             // padded v/scores leading dim (float4-aligned)

// ws layout (floats)
// scores aliases hidden: hidden dead after gemm_uv; scores (16*128*132=270336) fits.
#define HID_OFF 0
#define U_OFF   (NM*NH)                   // 524288
#define V_OFF   (U_OFF + NM*NH)           // 1048576
#define ACC_OFF (V_OFF + NB*NJP*NH)       // 1589248

// ---------------------------------------------------------------------------
// Kernel A: hidden = relu(C @ W1 + b1)   (2048x512)@(512x256)
// tile 32(M) x 64(N), BK=16, 256 threads, 2x4 per thread -> 256 blocks
// ---------------------------------------------------------------------------
__global__ __launch_bounds__(256) void gemm_hidden(
    const float* __restrict__ A,   // 2048 x 512
    const float* __restrict__ W,   // 512 x 256
    const float* __restrict__ bias,// 256
    float* __restrict__ out)       // 2048 x 256
{
    const int K = DIN, N = NH;
    __shared__ float As[16][34];   // k-major, pad to 34 (even -> aligned float2)
    __shared__ float Bs[16][68];   // pad 68 (16B-aligned rows)
    int m0 = blockIdx.x * 32;
    int n0 = blockIdx.y * 64;
    int tid = threadIdx.x;
    int tm = tid >> 4, tn = tid & 15;     // tm: 2 rows, tn: 4 cols
    int lm = tid >> 2, lk = (tid & 3) * 4; // A staging (threads 0..127)
    int bk = tid >> 4, bn = (tid & 15) * 4;// B staging (all 256)
    float acc[2][4] = {{0.f}};

    for (int k0 = 0; k0 < K; k0 += 16) {
        if (tid < 128) {
            float4 a4 = *(const float4*)&A[(m0 + lm) * K + k0 + lk];
            As[lk + 0][lm] = a4.x; As[lk + 1][lm] = a4.y;
            As[lk + 2][lm] = a4.z; As[lk + 3][lm] = a4.w;
        }
        float4 b4 = *(const float4*)&W[(k0 + bk) * N + n0 + bn];
        *(float4*)&Bs[bk][bn] = b4;
        __syncthreads();
        #pragma unroll
        for (int kk = 0; kk < 16; kk++) {
            float2 a2 = *(const float2*)&As[kk][tm * 2];
            float4 bv = *(const float4*)&Bs[kk][tn * 4];
            float ar[2] = {a2.x, a2.y};
            float br[4] = {bv.x, bv.y, bv.z, bv.w};
            #pragma unroll
            for (int r = 0; r < 2; r++)
                #pragma unroll
                for (int c = 0; c < 4; c++)
                    acc[r][c] += ar[r] * br[c];
        }
        __syncthreads();
    }
    int col = n0 + tn * 4;
    float4 bb = *(const float4*)&bias[col];
    float bcol[4] = {bb.x, bb.y, bb.z, bb.w};
    #pragma unroll
    for (int r = 0; r < 2; r++) {
        int row = m0 + tm * 2 + r;
        float4 o;
        o.x = fmaxf(acc[r][0] + bcol[0], 0.f);
        o.y = fmaxf(acc[r][1] + bcol[1], 0.f);
        o.z = fmaxf(acc[r][2] + bcol[2], 0.f);
        o.w = fmaxf(acc[r][3] + bcol[3], 0.f);
        *(float4*)&out[row * N + col] = o;
    }
}

// ---------------------------------------------------------------------------
// Kernel B: u = hidden@Wa + bp ; hv = hidden@Wb scattered into v[b][1+i][k]
// GEMM M=2048, N=512, K=256; tile 32x64 -> 512 blocks
// ---------------------------------------------------------------------------
__global__ __launch_bounds__(256) void gemm_uv(
    const float* __restrict__ hidden, // 2048 x 256
    const float* __restrict__ Wp,     // 512 x 256
    const float* __restrict__ bp,     // 256
    float* __restrict__ u,            // 2048 x 256
    float* __restrict__ v)            // 16 x NJP x 256
{
    const int K = NH;
    __shared__ float As[16][34];
    __shared__ float Bs[16][68];
    int m0 = blockIdx.x * 32;
    int n0 = blockIdx.y * 64;     // 0..448; n0<256 -> u, else v
    bool isU = (n0 < NH);
    int tid = threadIdx.x;
    int tm = tid >> 4, tn = tid & 15;
    int lm = tid >> 2, lk = (tid & 3) * 4;
    int bk = tid >> 4, bn = (tid & 15) * 4;
    float acc[2][4] = {{0.f}};

    for (int k0 = 0; k0 < K; k0 += 16) {
        if (tid < 128) {
            float4 a4 = *(const float4*)&hidden[(m0 + lm) * K + k0 + lk];
            As[lk + 0][lm] = a4.x; As[lk + 1][lm] = a4.y;
            As[lk + 2][lm] = a4.z; As[lk + 3][lm] = a4.w;
        }
        int c = k0 + bk;
        float4 b4;
        if (isU) b4 = *(const float4*)&Wp[c * NH + n0 + bn];
        else     b4 = *(const float4*)&Wp[(NH + c) * NH + (n0 - NH) + bn];
        *(float4*)&Bs[bk][bn] = b4;
        __syncthreads();
        #pragma unroll
        for (int kk = 0; kk < 16; kk++) {
            float2 a2 = *(const float2*)&As[kk][tm * 2];
            float4 bv = *(const float4*)&Bs[kk][tn * 4];
            float ar[2] = {a2.x, a2.y};
            float br[4] = {bv.x, bv.y, bv.z, bv.w};
            #pragma unroll
            for (int r = 0; r < 2; r++)
                #pragma unroll
                for (int cc = 0; cc < 4; cc++)
                    acc[r][cc] += ar[r] * br[cc];
        }
        __syncthreads();
    }
    if (isU) {
        int col = n0 + tn * 4;
        float4 bb = *(const float4*)&bp[col];
        #pragma unroll
        for (int r = 0; r < 2; r++) {
            int row = m0 + tm * 2 + r;
            float4 o;
            o.x = acc[r][0] + bb.x; o.y = acc[r][1] + bb.y;
            o.z = acc[r][2] + bb.z; o.w = acc[r][3] + bb.w;
            *(float4*)&u[row * NH + col] = o;
        }
    } else {
        int col = (n0 - NH) + tn * 4;
        #pragma unroll
        for (int r = 0; r < 2; r++) {
            int row = m0 + tm * 2 + r;
            int b = row >> 7, i = row & 127;
            float4 o;
            o.x = acc[r][0]; o.y = acc[r][1];
            o.z = acc[r][2]; o.w = acc[r][3];
            *(float4*)&v[(b * NJP + 1 + i) * NH + col] = o;
        }
    }
}

// ---------------------------------------------------------------------------
// rootv: v[b][0][k] = root @ Wb ; zero pad rows 129..131
// ---------------------------------------------------------------------------
__global__ __launch_bounds__(256) void rootv_kernel(
    const float* __restrict__ root, const float* __restrict__ Wp,
    float* __restrict__ v)
{
    int k = threadIdx.x;
    float acc = 0.f;
    for (int c = 0; c < NH; c++)
        acc += root[c] * Wp[(NH + c) * NH + k];
    #pragma unroll
    for (int b = 0; b < NB; b++) {
        v[(b * NJP) * NH + k] = acc;
        v[(b * NJP + 129) * NH + k] = 0.f;
        v[(b * NJP + 130) * NH + k] = 0.f;
        v[(b * NJP + 131) * NH + k] = 0.f;
    }
}

// ---------------------------------------------------------------------------
// arc_scores: scores[b,i,j] = sum_k relu(u[b,i,k]+v[b,j,k]) * wa[k]
// tile 32(i) x 32(j), k-chunks of 64 staged k-major in LDS; 2x2 per thread
// grid (16, 4, 5) = 320 blocks
// ---------------------------------------------------------------------------
__global__ __launch_bounds__(256) void arc_scores_kernel(
    const float* __restrict__ u, const float* __restrict__ v,
    const float* __restrict__ W_arc, float* __restrict__ scores)
{
    int b = blockIdx.x;
    int i0 = blockIdx.y * 32;
    int j0 = blockIdx.z * 32;
    int tid = threadIdx.x;
    __shared__ float us[64][33];
    __shared__ float vs[64][33];
    __shared__ float wa[NH];
    wa[tid] = W_arc[tid];

    int tx = tid & 15, ty = tid >> 4;   // tx: 2 j-cols, ty: 2 i-rows
    float acc[2][2] = {{0.f}};

    for (int k0 = 0; k0 < NH; k0 += 64) {
        #pragma unroll
        for (int h = 0; h < 2; h++) {
            int idx = tid + h * 256;       // 0..511
            int row = idx >> 4;            // 0..31
            int kq  = (idx & 15) * 4;      // 0..60
            float4 a4 = *(const float4*)&u[(b * NL + i0 + row) * NH + k0 + kq];
            us[kq + 0][row] = a4.x; us[kq + 1][row] = a4.y;
            us[kq + 2][row] = a4.z; us[kq + 3][row] = a4.w;
            int jr = j0 + row; if (jr > 131) jr = 131;
            float4 b4 = *(const float4*)&v[(b * NJP + jr) * NH + k0 + kq];
            vs[kq + 0][row] = b4.x; vs[kq + 1][row] = b4.y;
            vs[kq + 2][row] = b4.z; vs[kq + 3][row] = b4.w;
        }
        __syncthreads();
        #pragma unroll 8
        for (int kk = 0; kk < 64; kk++) {
            float w  = wa[k0 + kk];
            float u0 = us[kk][ty * 2], u1 = us[kk][ty * 2 + 1];
            float v0 = vs[kk][tx * 2], v1 = vs[kk][tx * 2 + 1];
            acc[0][0] += fmaxf(u0 + v0, 0.f) * w;
            acc[0][1] += fmaxf(u0 + v1, 0.f) * w;
            acc[1][0] += fmaxf(u1 + v0, 0.f) * w;
            acc[1][1] += fmaxf(u1 + v1, 0.f) * w;
        }
        __syncthreads();
    }
    #pragma unroll
    for (int r = 0; r < 2; r++) {
        #pragma unroll
        for (int c = 0; c < 2; c++) {
            int j = j0 + tx * 2 + c;
            if (j < NJP)
                scores[(size_t)(b * NL + i0 + ty * 2 + r) * NJP + j] = acc[r][c];
        }
    }
}

// ---------------------------------------------------------------------------
// loss: per (b,i) row -> arc softmax CE (over 129) + label head CE (45)
// shfl-based reductions; label head: 180 lanes = 45 tags x 4 k-chunks
// ---------------------------------------------------------------------------
__global__ __launch_bounds__(256) void loss_kernel(
    const float* __restrict__ scores, const float* __restrict__ u,
    const float* __restrict__ v, const float* __restrict__ W_lab,
    const float* __restrict__ b_lab, const int* __restrict__ slens,
    const int* __restrict__ arcs, const int* __restrict__ labels,
    float* __restrict__ accum)
{
    int bi = blockIdx.x;
    int b = bi >> 7, i = bi & 127;
    if (i >= slens[b]) return;

    int tid = threadIdx.x;
    int wid = tid >> 6, lane = tid & 63;
    __shared__ float red[4];
    __shared__ float bc[2];
    __shared__ float sel[NH];
    __shared__ float part[192];
    __shared__ float ll[48];

    const float* srow = scores + (size_t)bi * NJP;
    float x = (tid < NJ) ? srow[tid] : -INFINITY;

    // block max via shfl + tiny LDS combine
    float m = x;
    #pragma unroll
    for (int off = 32; off > 0; off >>= 1) m = fmaxf(m, __shfl_down(m, off));
    if (lane == 0) red[wid] = m;
    __syncthreads();
    if (tid == 0) bc[0] = fmaxf(fmaxf(red[0], red[1]), fmaxf(red[2], red[3]));
    __syncthreads();
    m = bc[0];

    float e = (tid < NJ) ? expf(x - m) : 0.f;
    float s = e;
    #pragma unroll
    for (int off = 32; off > 0; off >>= 1) s += __shfl_down(s, off);
    if (lane == 0) red[wid] = s;
    __syncthreads();
    if (tid == 0) bc[1] = red[0] + red[1] + red[2] + red[3];

    int arc = arcs[bi];
    // sel = relu(u_row + v[arc])
    sel[tid] = fmaxf(u[bi * NH + tid] + v[(b * NJP + arc) * NH + tid], 0.f);
    __syncthreads();

    float logZ = m + logf(bc[1]);

    if (tid < 180) {
        int tag = tid % 45, chunk = tid / 45;
        int k0 = chunk * 64;
        float p = 0.f;
        #pragma unroll 8
        for (int k = k0; k < k0 + 64; k++)
            p += sel[k] * W_lab[k * NTAGS + tag];
        part[tid] = p;
    }
    __syncthreads();
    if (tid < NTAGS)
        ll[tid] = part[tid] + part[tid + 45] + part[tid + 90] + part[tid + 135]
                  + b_lab[tid];
    __syncthreads();

    if (wid == 0) {
        float y = (lane < NTAGS) ? ll[lane] : -INFINITY;
        float m2 = y;
        #pragma unroll
        for (int off = 32; off > 0; off >>= 1) m2 = fmaxf(m2, __shfl_down(m2, off));
        m2 = __shfl(m2, 0);
        float e2 = (lane < NTAGS) ? expf(y - m2) : 0.f;
        #pragma unroll
        for (int off = 32; off > 0; off >>= 1) e2 += __shfl_down(e2, off);
        if (lane == 0) {
            float logZ2 = m2 + logf(e2);
            float lab_ce = logZ2 - ll[labels[bi]];
            float arc_ce = logZ - srow[arc];
            atomicAdd(accum, arc_ce + lab_ce);
        }
    }
}

// ---------------------------------------------------------------------------
// finalize: out = 0.5 * accum / max(sum(slens), 1)
// ---------------------------------------------------------------------------
__global__ void finalize_kernel(const float* __restrict__ accum,
                                const int* __restrict__ slens,
                                float* __restrict__ out)
{
    if (threadIdx.x == 0) {
        int d = 0;
        #pragma unroll
        for (int b = 0; b < NB; b++) d += slens[b];
        float denom = fmaxf((float)d, 1.f);
        out[0] = 0.5f * accum[0] / denom;
    }
}

extern "C" void kernel_launch(void* const* d_in, const int* in_sizes, int n_in,
                              void* d_out, int out_size, void* d_ws, size_t ws_size,
                              hipStream_t stream) {
    (void)in_sizes; (void)n_in; (void)out_size; (void)ws_size;
    const float* ctx   = (const float*)d_in[0];
    const int*   slens = (const int*)  d_in[1];
    const int*   arcs  = (const int*)  d_in[2];
    const int*   labs  = (const int*)  d_in[3];
    const float* W1    = (const float*)d_in[4];
    const float* b1    = (const float*)d_in[5];
    const float* root  = (const float*)d_in[6];
    const float* Wp    = (const float*)d_in[7];
    const float* bp    = (const float*)d_in[8];
    const float* W_arc = (const float*)d_in[9];
    const float* W_lab = (const float*)d_in[11];
    const float* b_lab = (const float*)d_in[12];
    float* out = (float*)d_out;

    float* ws     = (float*)d_ws;
    float* hidden = ws + HID_OFF;   // also reused as scores after gemm_uv
    float* u      = ws + U_OFF;
    float* v      = ws + V_OFF;
    float* accum  = ws + ACC_OFF;
    float* scores = hidden;

    hipMemsetAsync(accum, 0, sizeof(float), stream);

    gemm_hidden<<<dim3(NM / 32, NH / 64), 256, 0, stream>>>(ctx, W1, b1, hidden);
    rootv_kernel<<<1, 256, 0, stream>>>(root, Wp, v);
    gemm_uv<<<dim3(NM / 32, (2 * NH) / 64), 256, 0, stream>>>(hidden, Wp, bp, u, v);
    arc_scores_kernel<<<dim3(NB, 4, 5), 256, 0, stream>>>(u, v, W_arc, scores);
    loss_kernel<<<NM, 256, 0, stream>>>(scores, u, v, W_lab, b_lab,
                                        slens, arcs, labs, accum);
    finalize_kernel<<<1, 64, 0, stream>>>(accum, slens, out);
}